// Round 5
// baseline (175.170 us; speedup 1.0000x reference)
//
#include <hip/hip_runtime.h>
#include <math.h>

// Model collapses (softmax over a length-1 key axis == 1.0 => ctx == V) to a
// per-row MLP on biobert_cls [256,768]:
//   V      = bio @ ca_wv + ca_bv                 [256,256]
//   ctx    = LN(V @ ca_wo + ca_bo; ca_ln)
//   ffn    = relu(ctx @ w1 + b1) @ w2 + b2
//   outr   = LN(ctx + ffn; fn)
//   logits = outr @ fc_w + fc_b                  [256,5]
//
// R5: R4's bf16 weights (absmax 0.0156 proven) but 128 blocks x 2 rows x 512
// threads. Per-CU: weight stream 786KB (~5.1us at ~64B/cyc L2 interface)
// overlapped with ~5.1us VALU issue; 2x the CUs of R4. Threads map 1:1 onto
// the 2x256 outputs; ctx residual stays in-register.

#define WV_ELEMS   (768 * 256)
#define W256_ELEMS (256 * 256)

__device__ __forceinline__ unsigned short f2bf_rne(float x) {
    unsigned u = __float_as_uint(x);
    unsigned r = (u + 0x7fffu + ((u >> 16) & 1u)) >> 16;   // round-nearest-even
    return (unsigned short)r;
}
__device__ __forceinline__ float bf_lo(unsigned u) { return __uint_as_float(u << 16); }
__device__ __forceinline__ float bf_hi(unsigned u) { return __uint_as_float(u & 0xffff0000u); }

// Pack wv(768x256), wo, w1, w2 (256x256 each) into bf16 at d_ws.
// 98304 float4 slots = 384 blocks x 256 threads.
__global__ __launch_bounds__(256)
void cvt_weights(const float* __restrict__ wv, const float* __restrict__ wo,
                 const float* __restrict__ w1, const float* __restrict__ w2,
                 unsigned short* __restrict__ dst) {
    int i = blockIdx.x * 256 + threadIdx.x;    // float4 slot
    const float4* src; int li;
    if (i < 49152)      { src = (const float4*)wv; li = i; }
    else if (i < 65536) { src = (const float4*)wo; li = i - 49152; }
    else if (i < 81920) { src = (const float4*)w1; li = i - 65536; }
    else                { src = (const float4*)w2; li = i - 81920; }
    float4 v = src[li];
    ushort4 o;
    o.x = f2bf_rne(v.x); o.y = f2bf_rne(v.y); o.z = f2bf_rne(v.z); o.w = f2bf_rne(v.w);
    ((ushort4*)dst)[i] = o;
}

// Per-row LN stats; row = tid>>8 (2 rows), 4 waves per row-group.
// All 512 threads must call (uniform barriers).
__device__ __forceinline__ void ln_stats2(float x, int tid, float (*sred)[8],
                                          float& m, float& rs) {
    float sum = x, sq = x * x;
    #pragma unroll
    for (int o = 32; o > 0; o >>= 1) {
        sum += __shfl_down(sum, o);
        sq  += __shfl_down(sq,  o);
    }
    const int lane = tid & 63, r = tid >> 8, w = (tid >> 6) & 3;
    if (lane == 0) { sred[r][w] = sum; sred[r][4 + w] = sq; }
    __syncthreads();
    if ((tid & 255) == 0) {
        float S = sred[r][0] + sred[r][1] + sred[r][2] + sred[r][3];
        float Q = sred[r][4] + sred[r][5] + sred[r][6] + sred[r][7];
        float mm  = S * (1.0f / 256.0f);
        float var = Q * (1.0f / 256.0f) - mm * mm;   // biased var (jnp.var)
        sred[r][0] = mm;
        sred[r][1] = rsqrtf(fmaxf(var, 0.0f) + 1e-5f);
    }
    __syncthreads();
    m  = sred[r][0];
    rs = sred[r][1];
    __syncthreads();                                  // protect before reuse
}

__global__ __launch_bounds__(512)
void mlp_head_kernel(const float* __restrict__ bio,          // [256,768]
                     const unsigned short* __restrict__ wpack,
                     const float* __restrict__ bv, const float* __restrict__ bo,
                     const float* __restrict__ lng, const float* __restrict__ lnb,
                     const float* __restrict__ b1, const float* __restrict__ b2,
                     const float* __restrict__ fng, const float* __restrict__ fnb,
                     const float* __restrict__ fcw, const float* __restrict__ fcb,
                     float* __restrict__ out)                // [256,5]
{
    const int b   = blockIdx.x;     // rows 2b, 2b+1
    const int tid = threadIdx.x;
    const int q   = tid >> 6;       // K-group 0..7
    const int co  = tid & 63;       // channel quad: 4co..4co+3

    const unsigned short* wv16 = wpack;
    const unsigned short* wo16 = wpack + WV_ELEMS;
    const unsigned short* w116 = wo16 + W256_ELEMS;
    const unsigned short* w216 = w116 + W256_ELEMS;

    __shared__ float s_bio[2][768];
    __shared__ float s_act[2][256];
    __shared__ float s_part[8][2][256];
    __shared__ float s_red[2][8];

    for (int i = tid; i < 2 * 768; i += 512)
        ((float*)s_bio)[i] = bio[b * 1536 + i];
    __syncthreads();

    // GEMM partial: bf16 weights [k][256]; this thread: K rows q*KG..q*KG+KG-1,
    // channels 4co..4co+3, both activation rows. Trailing sync included.
    #define GEMM_BF16(W16, KG, SRC, SSTR) {                                   \
        float4 a0 = {0,0,0,0}, a1 = {0,0,0,0};                                \
        const uint2* wp = (const uint2*)(W16) + (q * (KG)) * 64 + co;         \
        const float* x0 = (SRC) + q * (KG);                                   \
        const float* x1 = (SRC) + (SSTR) + q * (KG);                          \
        _Pragma("unroll 16")                                                  \
        for (int k = 0; k < (KG); ++k) {                                      \
            uint2 u = wp[k * 64];                                             \
            float wa = bf_lo(u.x), wb = bf_hi(u.x);                           \
            float wc = bf_lo(u.y), wd = bf_hi(u.y);                           \
            float v0 = x0[k], v1 = x1[k];                                     \
            a0.x = fmaf(v0, wa, a0.x); a0.y = fmaf(v0, wb, a0.y);             \
            a0.z = fmaf(v0, wc, a0.z); a0.w = fmaf(v0, wd, a0.w);             \
            a1.x = fmaf(v1, wa, a1.x); a1.y = fmaf(v1, wb, a1.y);             \
            a1.z = fmaf(v1, wc, a1.z); a1.w = fmaf(v1, wd, a1.w);             \
        }                                                                     \
        ((float4*)s_part[q][0])[co] = a0;                                     \
        ((float4*)s_part[q][1])[co] = a1;                                     \
    }                                                                         \
    __syncthreads();

    // Thread tid owns output (rr = tid>>8, cc = tid&255).
    #define REDUCE1(V) {                                                      \
        float p_ = 0.f;                                                       \
        _Pragma("unroll")                                                     \
        for (int g = 0; g < 8; ++g) p_ += s_part[g][tid >> 8][tid & 255];     \
        V = p_;                                                               \
    }

    const int rr = tid >> 8, cc = tid & 255;

    // ---- V = bio @ wv + bv ----
    GEMM_BF16(wv16, 96, (const float*)s_bio, 768);
    {
        float p; REDUCE1(p);
        s_act[rr][cc] = p + bv[cc];
    }
    __syncthreads();

    // ---- t = V @ wo + bo ; ctx = LN(t) ----
    float ctx;
    GEMM_BF16(wo16, 32, (const float*)s_act, 256);
    {
        float p; REDUCE1(p);
        float t = p + bo[cc];
        float m, rs;
        ln_stats2(t, tid, s_red, m, rs);
        ctx = (t - m) * rs * lng[cc] + lnb[cc];
        s_act[rr][cc] = ctx;
    }
    __syncthreads();

    // ---- u = relu(ctx @ w1 + b1) ----
    GEMM_BF16(w116, 32, (const float*)s_act, 256);
    {
        float p; REDUCE1(p);
        s_act[rr][cc] = fmaxf(p + b1[cc], 0.0f);
    }
    __syncthreads();

    // ---- f = u @ w2 + b2 ; outr = LN(ctx + f) ----
    GEMM_BF16(w216, 32, (const float*)s_act, 256);
    {
        float p; REDUCE1(p);
        float o = p + b2[cc] + ctx;
        float m, rs;
        ln_stats2(o, tid, s_red, m, rs);
        s_act[rr][cc] = (o - m) * rs * fng[cc] + fnb[cc];
    }
    __syncthreads();

    // ---- logits = outr @ fc_w + fc_b  (fc_w is [256,5]) ----
    // wave 0 -> row 0, wave 4 -> row 1 (q&3)==0; lane l sums k = l+64e.
    if ((q & 3) == 0) {
        const int row  = q >> 2;
        const int lane = tid & 63;
        float acc[5] = {0, 0, 0, 0, 0};
        #pragma unroll
        for (int e = 0; e < 4; ++e) {
            int k = lane + 64 * e;
            float xv = s_act[row][k];
            #pragma unroll
            for (int c = 0; c < 5; ++c) acc[c] = fmaf(xv, fcw[k * 5 + c], acc[c]);
        }
        #pragma unroll
        for (int o2 = 32; o2 > 0; o2 >>= 1) {
            #pragma unroll
            for (int c = 0; c < 5; ++c) acc[c] += __shfl_down(acc[c], o2);
        }
        if (lane == 0) {
            #pragma unroll
            for (int c = 0; c < 5; ++c) out[(2 * b + row) * 5 + c] = acc[c] + fcb[c];
        }
    }
    #undef GEMM_BF16
    #undef REDUCE1
}

extern "C" void kernel_launch(void* const* d_in, const int* in_sizes, int n_in,
                              void* d_out, int out_size, void* d_ws, size_t ws_size,
                              hipStream_t stream) {
    // input order: 0:x 1:biobert_cls 2..25 gat/bn params (dead)
    // 26:ca_wq 27:ca_bq 28:ca_wk 29:ca_bk 30:ca_wv 31:ca_bv 32:ca_wo 33:ca_bo
    // 34:ca_ln_g 35:ca_ln_b 36:ffn_w1 37:ffn_b1 38:ffn_w2 39:ffn_b2
    // 40:fc_w 41:fc_b 42:fn_g 43:fn_b 44:edge_src 45:edge_dst 46:batch
    const float* bio = (const float*)d_in[1];
    const float* wv  = (const float*)d_in[30];
    const float* bv  = (const float*)d_in[31];
    const float* wo  = (const float*)d_in[32];
    const float* bo  = (const float*)d_in[33];
    const float* lng = (const float*)d_in[34];
    const float* lnb = (const float*)d_in[35];
    const float* w1  = (const float*)d_in[36];
    const float* b1  = (const float*)d_in[37];
    const float* w2  = (const float*)d_in[38];
    const float* b2  = (const float*)d_in[39];
    const float* fcw = (const float*)d_in[40];
    const float* fcb = (const float*)d_in[41];
    const float* fng = (const float*)d_in[42];
    const float* fnb = (const float*)d_in[43];
    float* out = (float*)d_out;
    unsigned short* wpack = (unsigned short*)d_ws;   // 786432 bf16 = 1.5 MB

    hipLaunchKernelGGL(cvt_weights, dim3(384), dim3(256), 0, stream,
                       wv, wo, w1, w2, wpack);
    hipLaunchKernelGGL(mlp_head_kernel, dim3(128), dim3(512), 0, stream,
                       bio, wpack, bv, bo, lng, lnb, b1, b2,
                       fng, fnb, fcw, fcb, out);
}

// Round 6
// 167.725 us; speedup vs baseline: 1.0444x; 1.0444x over previous
//
#include <hip/hip_runtime.h>
#include <math.h>

// Model collapses (softmax over a length-1 key axis == 1.0 => ctx == V) to a
// per-row MLP on biobert_cls [256,768]:
//   V      = bio @ ca_wv + ca_bv                 [256,256]
//   ctx    = LN(V @ ca_wo + ca_bo; ca_ln)
//   ffn    = relu(ctx @ w1 + b1) @ w2 + b2
//   outr   = LN(ctx + ffn; fn)
//   logits = outr @ fc_w + fc_b                  [256,5]
//
// R6: latency-bound diagnosis (R3/R4/R5 all ~30us despite 4x traffic deltas).
// Fix = TLP: 256 blocks x 1024 threads (16 waves/CU on every CU), 1 row per
// block, 16-way K-split, bf16 weights. Outstanding loads x4 vs R5; barrier
// drains overlap with other waves' loads.

#define WV_ELEMS   (768 * 256)
#define W256_ELEMS (256 * 256)

__device__ __forceinline__ unsigned short f2bf_rne(float x) {
    unsigned u = __float_as_uint(x);
    unsigned r = (u + 0x7fffu + ((u >> 16) & 1u)) >> 16;   // round-nearest-even
    return (unsigned short)r;
}
__device__ __forceinline__ float bf_lo(unsigned u) { return __uint_as_float(u << 16); }
__device__ __forceinline__ float bf_hi(unsigned u) { return __uint_as_float(u & 0xffff0000u); }

// Pack wv(768x256), wo, w1, w2 (256x256 each) into bf16 at d_ws.
// 98304 float4 slots = 384 blocks x 256 threads.
__global__ __launch_bounds__(256)
void cvt_weights(const float* __restrict__ wv, const float* __restrict__ wo,
                 const float* __restrict__ w1, const float* __restrict__ w2,
                 unsigned short* __restrict__ dst) {
    int i = blockIdx.x * 256 + threadIdx.x;    // float4 slot
    const float4* src; int li;
    if (i < 49152)      { src = (const float4*)wv; li = i; }
    else if (i < 65536) { src = (const float4*)wo; li = i - 49152; }
    else if (i < 81920) { src = (const float4*)w1; li = i - 65536; }
    else                { src = (const float4*)w2; li = i - 81920; }
    float4 v = src[li];
    ushort4 o;
    o.x = f2bf_rne(v.x); o.y = f2bf_rne(v.y); o.z = f2bf_rne(v.z); o.w = f2bf_rne(v.w);
    ((ushort4*)dst)[i] = o;
}

// LN stats over the 256 values held by threads tid<256 (x must be 0 for
// tid>=256). All 1024 threads call (uniform barriers).
__device__ __forceinline__ void ln_stats(float x, int tid, float* sred,
                                         float& m, float& rs) {
    float sum = x, sq = x * x;
    #pragma unroll
    for (int o = 32; o > 0; o >>= 1) {
        sum += __shfl_down(sum, o);
        sq  += __shfl_down(sq,  o);
    }
    const int lane = tid & 63, w = tid >> 6;
    if (lane == 0 && w < 4) { sred[w] = sum; sred[4 + w] = sq; }
    __syncthreads();
    if (tid == 0) {
        float S = sred[0] + sred[1] + sred[2] + sred[3];
        float Q = sred[4] + sred[5] + sred[6] + sred[7];
        float mm  = S * (1.0f / 256.0f);
        float var = Q * (1.0f / 256.0f) - mm * mm;   // biased var (jnp.var)
        sred[0] = mm;
        sred[1] = rsqrtf(fmaxf(var, 0.0f) + 1e-5f);
    }
    __syncthreads();
    m  = sred[0];
    rs = sred[1];
    __syncthreads();                                  // protect before reuse
}

__global__ __launch_bounds__(1024)
void mlp_head_kernel(const float* __restrict__ bio,          // [256,768]
                     const unsigned short* __restrict__ wpack,
                     const float* __restrict__ bv, const float* __restrict__ bo,
                     const float* __restrict__ lng, const float* __restrict__ lnb,
                     const float* __restrict__ b1, const float* __restrict__ b2,
                     const float* __restrict__ fng, const float* __restrict__ fnb,
                     const float* __restrict__ fcw, const float* __restrict__ fcb,
                     float* __restrict__ out)                // [256,5]
{
    const int b   = blockIdx.x;     // row
    const int tid = threadIdx.x;
    const int q   = tid >> 6;       // K-group 0..15 (wave id)
    const int co  = tid & 63;       // channel quad: 4co..4co+3

    const unsigned short* wv16 = wpack;
    const unsigned short* wo16 = wpack + WV_ELEMS;
    const unsigned short* w116 = wo16 + W256_ELEMS;
    const unsigned short* w216 = w116 + W256_ELEMS;

    __shared__ float s_bio[768];
    __shared__ float s_act[256];
    __shared__ float s_part[16][256];
    __shared__ float s_red[8];

    if (tid < 768) s_bio[tid] = bio[b * 768 + tid];
    __syncthreads();

    // GEMM partial: bf16 weights [k][256]; this thread covers K rows
    // q*KG..q*KG+KG-1, channels 4co..4co+3. Trailing sync included.
    #define GEMM_BF16(W16, KG, SRC) {                                         \
        float4 a0 = {0, 0, 0, 0};                                             \
        const uint2* wp = (const uint2*)(W16) + (q * (KG)) * 64 + co;         \
        const float* x0 = (SRC) + q * (KG);                                   \
        _Pragma("unroll 16")                                                  \
        for (int k = 0; k < (KG); ++k) {                                      \
            uint2 u = wp[k * 64];                                             \
            float v0 = x0[k];                                                 \
            a0.x = fmaf(v0, bf_lo(u.x), a0.x);                                \
            a0.y = fmaf(v0, bf_hi(u.x), a0.y);                                \
            a0.z = fmaf(v0, bf_lo(u.y), a0.z);                                \
            a0.w = fmaf(v0, bf_hi(u.y), a0.w);                                \
        }                                                                     \
        ((float4*)s_part[q])[co] = a0;                                        \
    }                                                                         \
    __syncthreads();

    // Thread tid<256 owns output channel tid.
    #define REDUCE1(V) {                                                      \
        float p_ = 0.f;                                                       \
        _Pragma("unroll")                                                     \
        for (int g = 0; g < 16; ++g) p_ += s_part[g][tid];                    \
        V = p_;                                                               \
    }

    // ---- V = bio @ wv + bv ----
    GEMM_BF16(wv16, 48, s_bio);
    if (tid < 256) {
        float p; REDUCE1(p);
        s_act[tid] = p + bv[tid];
    }
    __syncthreads();

    // ---- t = V @ wo + bo ; ctx = LN(t) ----
    float ctx = 0.f;                       // live in tid<256 only
    GEMM_BF16(wo16, 16, s_act);
    {
        float t = 0.f;
        if (tid < 256) {
            float p; REDUCE1(p);
            t = p + bo[tid];
        }
        float m, rs;
        ln_stats(t, tid, s_red, m, rs);
        if (tid < 256) {
            ctx = (t - m) * rs * lng[tid] + lnb[tid];
            s_act[tid] = ctx;
        }
    }
    __syncthreads();

    // ---- u = relu(ctx @ w1 + b1) ----
    GEMM_BF16(w116, 16, s_act);
    if (tid < 256) {
        float p; REDUCE1(p);
        s_act[tid] = fmaxf(p + b1[tid], 0.0f);
    }
    __syncthreads();

    // ---- f = u @ w2 + b2 ; outr = LN(ctx + f) ----
    GEMM_BF16(w216, 16, s_act);
    {
        float o = 0.f;
        if (tid < 256) {
            float p; REDUCE1(p);
            o = p + b2[tid] + ctx;
        }
        float m, rs;
        ln_stats(o, tid, s_red, m, rs);
        if (tid < 256) s_act[tid] = (o - m) * rs * fng[tid] + fnb[tid];
    }
    __syncthreads();

    // ---- logits = outr @ fc_w + fc_b  (fc_w is [256,5]) ----
    // wave 0: lane l sums k = l + 64e over all 5 classes.
    if (q == 0) {
        float acc[5] = {0, 0, 0, 0, 0};
        #pragma unroll
        for (int e = 0; e < 4; ++e) {
            int k = co + 64 * e;
            float xv = s_act[k];
            #pragma unroll
            for (int c = 0; c < 5; ++c) acc[c] = fmaf(xv, fcw[k * 5 + c], acc[c]);
        }
        #pragma unroll
        for (int o2 = 32; o2 > 0; o2 >>= 1) {
            #pragma unroll
            for (int c = 0; c < 5; ++c) acc[c] += __shfl_down(acc[c], o2);
        }
        if (co == 0) {
            #pragma unroll
            for (int c = 0; c < 5; ++c) out[b * 5 + c] = acc[c] + fcb[c];
        }
    }
    #undef GEMM_BF16
    #undef REDUCE1
}

extern "C" void kernel_launch(void* const* d_in, const int* in_sizes, int n_in,
                              void* d_out, int out_size, void* d_ws, size_t ws_size,
                              hipStream_t stream) {
    // input order: 0:x 1:biobert_cls 2..25 gat/bn params (dead)
    // 26:ca_wq 27:ca_bq 28:ca_wk 29:ca_bk 30:ca_wv 31:ca_bv 32:ca_wo 33:ca_bo
    // 34:ca_ln_g 35:ca_ln_b 36:ffn_w1 37:ffn_b1 38:ffn_w2 39:ffn_b2
    // 40:fc_w 41:fc_b 42:fn_g 43:fn_b 44:edge_src 45:edge_dst 46:batch
    const float* bio = (const float*)d_in[1];
    const float* wv  = (const float*)d_in[30];
    const float* bv  = (const float*)d_in[31];
    const float* wo  = (const float*)d_in[32];
    const float* bo  = (const float*)d_in[33];
    const float* lng = (const float*)d_in[34];
    const float* lnb = (const float*)d_in[35];
    const float* w1  = (const float*)d_in[36];
    const float* b1  = (const float*)d_in[37];
    const float* w2  = (const float*)d_in[38];
    const float* b2  = (const float*)d_in[39];
    const float* fcw = (const float*)d_in[40];
    const float* fcb = (const float*)d_in[41];
    const float* fng = (const float*)d_in[42];
    const float* fnb = (const float*)d_in[43];
    float* out = (float*)d_out;
    unsigned short* wpack = (unsigned short*)d_ws;   // 786432 bf16 = 1.5 MB

    hipLaunchKernelGGL(cvt_weights, dim3(384), dim3(256), 0, stream,
                       wv, wo, w1, w2, wpack);
    hipLaunchKernelGGL(mlp_head_kernel, dim3(256), dim3(1024), 0, stream,
                       bio, wpack, bv, bo, lng, lnb, b1, b2,
                       fng, fnb, fcw, fcb, out);
}